// Round 3
// baseline (178.259 us; speedup 1.0000x reference)
//
#include <hip/hip_runtime.h>

#define NTOK 1024
#define DDIM 128

typedef _Float16 f16;
typedef _Float16 f16x2v __attribute__((ext_vector_type(2)));
typedef _Float16 f16x4 __attribute__((ext_vector_type(4)));
typedef _Float16 f16x8 __attribute__((ext_vector_type(8)));
typedef float f32x16 __attribute__((ext_vector_type(16)));
typedef unsigned int uint;
typedef long i64;

union PFrag {
  float f[4];
  f16x8 h;
};

#define AS1 __attribute__((address_space(1)))
#define AS3 __attribute__((address_space(3)))
#define NLOG2E -1.44269504f

// ---------------- fused prepass (unchanged) ---------------------------------
// blocks [0,512):  x -> x8n (normalized fp8-e4m3) + xhT (unscaled f16 transp)
// blocks [512,768): beta -> betaTp: f16 pairs [m>>1][i][2], pre-scaled -log2e
__global__ __launch_bounds__(256) void prep_fused(
    const float* __restrict__ x, const float* __restrict__ beta,
    unsigned char* __restrict__ x8n, f16* __restrict__ xhT,
    uint* __restrict__ betaTp) {
  __shared__ __align__(16) char psm[128 * 132 * 2];
  int bx = blockIdx.x;
  int t = threadIdx.x;
  if (bx < 512) {
    f16* sT = (f16*)psm;  // [128][132]
    int bc = bx & 63;
    int nt = bx >> 6;
    int n0 = nt * 128;
    const float4* xv = (const float4*)(x + ((size_t)bc * NTOK + n0) * DDIM);
#pragma unroll
    for (int k = 0; k < 16; ++k) {
      int idx = t + 256 * k;
      int row = idx >> 5;
      int c4 = idx & 31;
      float4 v = xv[(size_t)row * 32 + c4];
      float ss = v.x * v.x + v.y * v.y + v.z * v.z + v.w * v.w;
      ss += __shfl_xor(ss, 1);
      ss += __shfl_xor(ss, 2);
      ss += __shfl_xor(ss, 4);
      ss += __shfl_xor(ss, 8);
      ss += __shfl_xor(ss, 16);
      float rn = (ss > 0.f) ? rsqrtf(ss) : 0.f;
      int p01 = __builtin_amdgcn_cvt_pk_fp8_f32(v.x * rn, v.y * rn, 0, false);
      int p03 = __builtin_amdgcn_cvt_pk_fp8_f32(v.z * rn, v.w * rn, p01, true);
      *(int*)(x8n + ((size_t)bc * NTOK + n0 + row) * DDIM + c4 * 4) = p03;
      f16x4 hv = {(f16)v.x, (f16)v.y, (f16)v.z, (f16)v.w};
      *(f16x4*)(sT + row * 132 + c4 * 4) = hv;
    }
    __syncthreads();
    int dr = t >> 1;
    int half = t & 1;
    f16* dst = xhT + ((size_t)bc * DDIM + dr) * NTOK + n0 + 64 * half;
#pragma unroll
    for (int s = 0; s < 8; ++s) {
      f16x8 tmp;
#pragma unroll
      for (int j = 0; j < 8; ++j)
        tmp[j] = sT[(64 * half + s * 8 + j) * 132 + dr];
      *(f16x8*)(dst + s * 8) = tmp;
    }
  } else {
    float(*s)[65] = (float(*)[65])psm;
    int bb = bx - 512;
    int bi = bb & 15;   // i tile
    int bj = bb >> 4;   // m tile
    int r = t >> 4;
    int c4 = (t & 15) * 4;
#pragma unroll
    for (int rr = 0; rr < 64; rr += 16) {
      float4 v = *(const float4*)(beta + (size_t)(bi * 64 + r + rr) * NTOK +
                                  bj * 64 + c4);
      s[r + rr][c4] = v.x;
      s[r + rr][c4 + 1] = v.y;
      s[r + rr][c4 + 2] = v.z;
      s[r + rr][c4 + 3] = v.w;
    }
    __syncthreads();
    int il = t & 63;
#pragma unroll
    for (int rr = 0; rr < 8; ++rr) {
      int m2 = (t >> 6) + 4 * rr;  // 0..31
      float b0 = s[il][2 * m2] * NLOG2E;
      float b1 = s[il][2 * m2 + 1] * NLOG2E;
      uint u = __builtin_bit_cast(uint, __builtin_amdgcn_cvt_pkrtz(b0, b1));
      betaTp[(size_t)(bj * 32 + m2) * NTOK + bi * 64 + il] = u;
    }
  }
}

// ---------------- main ------------------------------------------------------
// 1024 blocks x 256 threads (4 waves = 2 i-groups x 2 m-halves), one 64-row
// q-tile per block, ~3 blocks/CU. Latency decoupling vs prior rounds:
//  - betas prefetched ONE tile ahead (ping-pong regs): sigmoid never waits L2
//  - GEMM1 A-frags read DIRECT from global/L2 (no sXm8 staging, no LDS reads)
//  - LDS only stages sXmT (16KB dbuf); smaller barrier domain + multiple
//    independent blocks per CU de-phase the GEMM/sigmoid bursts.
__global__ __launch_bounds__(256, 3) void cos_att_main(
    const unsigned char* __restrict__ x8n, const f16* __restrict__ xhT,
    const uint* __restrict__ betaTp, float* __restrict__ out) {
  __shared__ __align__(16) char smem[32768];  // dbuf: 2 x sXmT 16K; epi 32K
  int bx = blockIdx.x;
  int bc = bx & 63;
  int qh = bx >> 6;  // 0..15
  int q0 = qh * 64;

  int t = threadIdx.x;
  int lane = t & 63;
  int w = t >> 6;  // 0..3
  int l31 = lane & 31;
  int hi = lane >> 5;
  int i_str = (w >> 1) * 32;  // 0,32
  int m_str = (w & 1) * 32;

  // Xq B-frags (fp8) for this wave's 32 q rows (16 VGPRs)
  i64 xq8[8];
  {
    const unsigned char* base =
        x8n + ((size_t)bc * NTOK + q0 + i_str + l31) * DDIM + hi * 8;
#pragma unroll
    for (int kk = 0; kk < 8; ++kk) xq8[kk] = *(const i64*)(base + kk * 16);
  }

  // stage sXmT tile (128 d-rows x 128B f16), 16B-chunk XOR by (d&7)
  auto stageT = [&](int mi, int b) {
    int m0 = mi * 64;
    char* ldst = smem + b * 16384;
    int lr = lane >> 3;
    int cp = lane & 7;
    const f16* gb = xhT + (size_t)bc * DDIM * NTOK + m0;
#pragma unroll
    for (int j = 0; j < 4; ++j) {
      int d = 32 * j + 8 * w + lr;  // 0..127, d&7 == lr
      int g = cp ^ lr;
      const f16* gp = gb + (size_t)d * NTOK + g * 8;
      __builtin_amdgcn_global_load_lds((const AS1 uint*)gp,
                                       (AS3 uint*)(ldst + (32 * j + 8 * w) * 128),
                                       16, 0, 0);
    }
  };

  // beta f16-pair loads for tile mi into an 8-dword register array
  auto loadBeta = [&](int mi, uint (&bvp)[8]) {
    const uint* bbase =
        betaTp + (size_t)((mi * 64 + m_str) >> 1) * NTOK + q0 + i_str + l31;
#pragma unroll
    for (int rp = 0; rp < 8; ++rp) {
      int m2l = (rp & 1) + 4 * (rp >> 1) + 2 * hi;
      bvp[rp] = bbase[(size_t)m2l * NTOK];
    }
  };

  stageT(0, 0);

  uint bvp0[8], bvp1[8];
  loadBeta(0, bvp0);

  f32x16 o[4];
#pragma unroll
  for (int dt = 0; dt < 4; ++dt)
#pragma unroll
    for (int z = 0; z < 16; ++z) o[dt][z] = 0.f;

  // one m-tile iteration; bvpC = betas for THIS tile (already landed),
  // bvpN = array to prefetch NEXT tile's betas into.
  auto body = [&](int mi, uint (&bvpC)[8], uint (&bvpN)[8]) {
    int b = mi & 1;
    int m0 = mi * 64;
    __syncthreads();  // sXmT[b] DMA drained; all waves past reads of buf 1-b

    // GEMM1 A-frags: direct from global (L2-resident x8n), 8 indep b64 loads
    i64 xa[8];
    {
      const unsigned char* abase =
          x8n + ((size_t)bc * NTOK + m0 + m_str + l31) * DDIM + hi * 8;
#pragma unroll
      for (int kk = 0; kk < 8; ++kk) xa[kk] = *(const i64*)(abase + kk * 16);
    }
    if (mi < 15) {
      stageT(mi + 1, 1 - b);  // DMA for next tile, drained at next barrier
      loadBeta(mi + 1, bvpN); // prefetch: lands during this tile's compute
    }

    const char* ldst = smem + b * 16384;

    // GEMM1 (fp8): S^T = Xm . Xq^T
    f32x16 s;
#pragma unroll
    for (int z = 0; z < 16; ++z) s[z] = 0.f;
    __builtin_amdgcn_s_setprio(1);
#pragma unroll
    for (int kk = 0; kk < 8; ++kk)
      s = __builtin_amdgcn_mfma_f32_32x32x16_fp8_fp8(xa[kk], xq8[kk], s, 0, 0, 0);
    __builtin_amdgcn_s_setprio(0);

    // sigmoid (s dies here), P packed to f16x2 dwords; betas pre-landed
    PFrag b0, b1;
    {
      float pk[8];
#pragma unroll
      for (int rp = 0; rp < 8; ++rp) {
        f16x2v bh = __builtin_bit_cast(f16x2v, bvpC[rp]);
        // betaTp pre-scaled by -log2(e): P = rcp(1 + exp2(b'*cos))
        float e0 = __builtin_amdgcn_exp2f((float)bh[0] * s[2 * rp]);
        float e1 = __builtin_amdgcn_exp2f((float)bh[1] * s[2 * rp + 1]);
        float p0 = __builtin_amdgcn_rcpf(1.0f + e0);
        float p1 = __builtin_amdgcn_rcpf(1.0f + e1);
        pk[rp] = __builtin_bit_cast(float, __builtin_amdgcn_cvt_pkrtz(p0, p1));
      }
      float qk[8];
#pragma unroll
      for (int rp = 0; rp < 8; ++rp) qk[rp] = __shfl_xor(pk[rp], 32);
      b0.f[0] = hi ? qk[2] : pk[0];
      b0.f[1] = hi ? qk[3] : pk[1];
      b0.f[2] = hi ? pk[2] : qk[0];
      b0.f[3] = hi ? pk[3] : qk[1];
      b1.f[0] = hi ? qk[6] : pk[4];
      b1.f[1] = hi ? qk[7] : pk[5];
      b1.f[2] = hi ? pk[6] : qk[4];
      b1.f[3] = hi ? pk[7] : qk[5];
    }

    // GEMM2 (f16): O^T[d][i] += XmT . P
    __builtin_amdgcn_s_setprio(1);
#pragma unroll
    for (int dt = 0; dt < 4; ++dt) {
      int d = dt * 32 + l31;
      const char* rowT = ldst + d * 128;
      int dx = d & 7;
      int g0 = (m_str >> 3) + hi;
      f16x8 a0 = *(const f16x8*)(rowT + ((g0 ^ dx) * 16));
      f16x8 a1 = *(const f16x8*)(rowT + (((g0 + 2) ^ dx) * 16));
      o[dt] = __builtin_amdgcn_mfma_f32_32x32x16_f16(a0, b0.h, o[dt], 0, 0, 0);
      o[dt] = __builtin_amdgcn_mfma_f32_32x32x16_f16(a1, b1.h, o[dt], 0, 0, 0);
    }
    __builtin_amdgcn_s_setprio(0);
  };

  // explicit parity unroll: beta ping-pong with compile-time array choice
  for (int mt = 0; mt < 8; ++mt) {
    body(2 * mt, bvp0, bvp1);
    body(2 * mt + 1, bvp1, bvp0);
  }

  // epilogue: m-half pair-reduce + transpose via LDS.
  // sO logical [64][128] f32 with 16B-chunk XOR by (row&7): float4 I/O.
  float* sO = (float*)smem;  // 32KB exactly
  int mh = w & 1;
  int row = i_str + l31;  // 0..63
  int rb = row & 7;
  __syncthreads();
  if (mh == 0) {
#pragma unroll
    for (int dt = 0; dt < 4; ++dt)
#pragma unroll
      for (int r4 = 0; r4 < 4; ++r4) {
        int c = dt * 8 + 2 * r4 + hi;  // 16B chunk: d = 4*c .. 4*c+3
        float4 v = {o[dt][4 * r4], o[dt][4 * r4 + 1], o[dt][4 * r4 + 2],
                    o[dt][4 * r4 + 3]};
        *(float4*)(sO + row * 128 + ((c ^ rb) * 4)) = v;
      }
  }
  __syncthreads();
  if (mh == 1) {
#pragma unroll
    for (int dt = 0; dt < 4; ++dt)
#pragma unroll
      for (int r4 = 0; r4 < 4; ++r4) {
        int c = dt * 8 + 2 * r4 + hi;
        float4* pp = (float4*)(sO + row * 128 + ((c ^ rb) * 4));
        float4 v = *pp;
        v.x += o[dt][4 * r4];
        v.y += o[dt][4 * r4 + 1];
        v.z += o[dt][4 * r4 + 2];
        v.w += o[dt][4 * r4 + 3];
        *pp = v;
      }
  }
  __syncthreads();
  float* og = out + ((size_t)bc * NTOK + q0) * DDIM;
#pragma unroll
  for (int k = 0; k < 8; ++k) {
    int idx = t + 256 * k;
    int r = idx >> 5;   // 0..63
    int c4 = idx & 31;  // 16B chunk
    *(float4*)(og + (size_t)r * DDIM + c4 * 4) =
        *(const float4*)(sO + r * 128 + ((c4 ^ (r & 7)) * 4));
  }
}

extern "C" void kernel_launch(void* const* d_in, const int* in_sizes, int n_in,
                              void* d_out, int out_size, void* d_ws,
                              size_t ws_size, hipStream_t stream) {
  const float* x = (const float*)d_in[0];
  const float* beta = (const float*)d_in[1];
  float* out = (float*)d_out;

  char* ws = (char*)d_ws;
  unsigned char* x8n = (unsigned char*)ws;  // 8 MB
  f16* xhT = (f16*)(ws + (8 << 20));        // 16 MB
  uint* betaTp = (uint*)(ws + (24 << 20));  // 2 MB

  prep_fused<<<768, 256, 0, stream>>>(x, beta, x8n, xhT, betaTp);
  cos_att_main<<<1024, 256, 0, stream>>>(x8n, xhT, betaTp, out);
}